// Round 11
// baseline (3414.298 us; speedup 1.0000x reference)
//
#include <hip/hip_runtime.h>

// ConditionalCNF via MFMA (round 16): single-half waves + VGPR<=64 tier.
// r15 post-mortem: permlane fix verified (absmax bit-identical) but 0 speed
// -- the exchange latency was already hidden; idle is residency-limited.
// Occupancy record: 88 VGPR -> 22.6%, 68-84 -> ~31% (r10's win tracked the
// VGPR drop), wave capacity halves at VGPR=64 (m69) -- the one untested
// tier.  This round: each wave carries ONE sample-half (32 samples; lanes l
// and l^32 redundantly hold the same sample with complementary k-chunks --
// state stays bitwise identical because kz/dlog come from the symmetric
// xsum32).  Halves c1v (-16 VGPR) and z/P state; drops one xsum32/stage;
// grid doubles to B/128 blocks.  __launch_bounds__(256, 8) forces the
// allocator to <=64 VGPR.  Per-sample math is byte-identical to r15.
//
// Layouts (HW-verified per guide m74/m101):
//   A-frag 32x32x16:  A[m=lane&31][k=(lane>>5)*8+j]
//   B-frag 32x32x16:  B[k=(lane>>5)*8+j][n=lane&31]
//   C/D:              col=lane&31, row=(reg&3)+8*(reg>>2)+4*(lane>>5)

typedef __attribute__((ext_vector_type(8))) short short8;
typedef __attribute__((ext_vector_type(2))) float float2v;
typedef __attribute__((ext_vector_type(16))) float floatx16;

constexpr int NSTEPS = 20;
constexpr float SCL = 2.8853900817779268f;   // 2*log2(e)

struct U128 { unsigned a, b, c, d; };

__device__ __forceinline__ float fexp2(float x) {
#if __has_builtin(__builtin_amdgcn_exp2f)
    return __builtin_amdgcn_exp2f(x);
#else
    return exp2f(x);
#endif
}

__device__ __forceinline__ float2v vfma(float2v a, float2v b, float2v c) {
#if __has_builtin(__builtin_elementwise_fma)
    return __builtin_elementwise_fma(a, b, c);
#else
    float2v d; d.x = fmaf(a.x, b.x, c.x); d.y = fmaf(a.y, b.y, c.y); return d;
#endif
}

// packed tanh, pre-scaled inputs xs = 2*log2(e)*x.  tanh = 1 - 2/(exp2+1),
// ONE rcp per pair via reciprocal sharing; all constants inline.
__device__ __forceinline__ float2v tanh_pk(float2v xs) {
    const float ex = fexp2(xs.x);
    const float ey = fexp2(xs.y);
    const float dx = ex + 1.0f;
    const float dy = ey + 1.0f;
    const float rr = __builtin_amdgcn_rcpf(dx * dy);
    const float q  = rr * -2.0f;
    return float2v{fmaf(q, dy, 1.0f), fmaf(q, dx, 1.0f)};
}

__device__ __forceinline__ unsigned cvtpk_bf16(float a, float b) {
    unsigned r;
    asm("v_cvt_pk_bf16_f32 %0, %1, %2" : "=v"(r) : "v"(a), "v"(b));
    return r;
}

__device__ __forceinline__ unsigned pack2bf(float a, float b) {
    unsigned ua = __builtin_bit_cast(unsigned, a) + 0x8000u;
    unsigned ub = __builtin_bit_cast(unsigned, b) + 0x8000u;
    return __builtin_amdgcn_perm(ub, ua, 0x07060302u);
}
__device__ __forceinline__ unsigned pack2bf_trunc(float2v v) {
    return __builtin_amdgcn_perm(__builtin_bit_cast(unsigned, v.y),
                                 __builtin_bit_cast(unsigned, v.x), 0x07060302u);
}
__device__ __forceinline__ float bf2f(unsigned bf) {
    return __builtin_bit_cast(float, bf << 16);
}

// x + x[lane^32] on the VALU pipe (verified r15, absmax bit-identical).
// Two distinct "+v" operands cannot alias; after v_permlane32_swap_b32 a,b
// (a_hi <-> b_lo), a+b is the symmetric pair-sum for every lane.
__device__ __forceinline__ float xsum32(float x) {
    float a = x, b = x;
    asm("v_permlane32_swap_b32 %0, %1" : "+v"(a), "+v"(b));
    return a + b;
}

__global__ __launch_bounds__(256, 8) void cnf_mfma(
    const float* __restrict__ Tin, const float* __restrict__ cond,
    const float* __restrict__ W1, const float* __restrict__ b1,
    const float* __restrict__ W2, const float* __restrict__ b2,
    const float* __restrict__ W3, const float* __restrict__ b3,
    float* __restrict__ out, int B)
{
    const int tid   = threadIdx.x;
    const int lane  = tid & 63;
    const int wbase = blockIdx.x * 128 + (tid >> 6) * 32;  // 32 samples/wave

    const int c  = lane & 31;          // D col = sample col; W2 row (A m)
    const int hi = lane >> 5;          // k-group for frags; D row-half

    const float is2 = 1.0f / (SCL * SCL);

    // ---- W2 A-frags: A[m=c][k = 16t + hi*8 + j], hi/lo bf16 split ----
    short8 Whi[2], Wlo[2];
#pragma unroll
    for (int t = 0; t < 2; ++t) {
        const float* w2r = W2 + c * 32 + 16 * t + hi * 8;
        unsigned hu[4], lu[4];
#pragma unroll
        for (int p = 0; p < 4; ++p) {
            const float w0 = SCL * w2r[2 * p], w1v = SCL * w2r[2 * p + 1];
            const unsigned h0 = (__builtin_bit_cast(unsigned, w0) + 0x8000u) >> 16;
            const unsigned h1 = (__builtin_bit_cast(unsigned, w1v) + 0x8000u) >> 16;
            hu[p] = h0 | (h1 << 16);
            lu[p] = pack2bf(w0 - bf2f(h0), w1v - bf2f(h1));
        }
        Whi[t] = __builtin_bit_cast(short8, U128{hu[0], hu[1], hu[2], hu[3]});
        Wlo[t] = __builtin_bit_cast(short8, U128{lu[0], lu[1], lu[2], lu[3]});
    }

    // ---- per-lane D-row constants: u(reg) = (reg&3) + 8*(reg>>2) + 4*hi ----
    floatx16 cinit;
    float2v w3p[8];
#pragma unroll
    for (int g = 0; g < 8; ++g) {
        const int u0 = ((2 * g) & 3) + 8 * (g >> 1) + 4 * hi;
        cinit[2 * g]     = SCL * b2[u0];
        cinit[2 * g + 1] = SCL * b2[u0 + 1];
        w3p[g] = float2v{W3[u0], W3[u0 + 1]};
    }

    // ---- layer-1 constants: k(t,j) = 16t + hi*8 + j ----
    float2v w1zv[2][4];
#pragma unroll
    for (int t = 0; t < 2; ++t)
#pragma unroll
        for (int p = 0; p < 4; ++p) {
            const int k = 16 * t + hi * 8 + 2 * p;
            w1zv[t][p] = float2v{SCL * W1[k * 9], SCL * W1[(k + 1) * 9]};
        }

    const int sgu = wbase + c;               // this lane's (only) sample
    int s0 = sgu; if (s0 > B - 1) s0 = B - 1;

    float cd0[8];
    {
        const float4* c4 = reinterpret_cast<const float4*>(cond + (size_t)s0 * 8);
        const float4 ca = c4[0], cb = c4[1];
        cd0[0]=ca.x; cd0[1]=ca.y; cd0[2]=ca.z; cd0[3]=ca.w;
        cd0[4]=cb.x; cd0[5]=cb.y; cd0[6]=cb.z; cd0[7]=cb.w;
    }

    // c1v[t][p]: s*(b1 + cond.W1row) for k = 16t + hi*8 + {2p,2p+1}
    float2v c1v[2][4];
#pragma unroll
    for (int t = 0; t < 2; ++t) {
        float c1a[8];
#pragma unroll
        for (int j = 0; j < 8; ++j) {
            const int k = 16 * t + hi * 8 + j;
            const float* wr = W1 + k * 9 + 1;
            float a0 = b1[k];
#pragma unroll
            for (int jj = 0; jj < 8; ++jj) a0 = fmaf(cd0[jj], wr[jj], a0);
            c1a[j] = SCL * a0;
        }
#pragma unroll
        for (int p = 0; p < 4; ++p)
            c1v[t][p] = float2v{c1a[2 * p], c1a[2 * p + 1]};
    }

    const float b3v = b3[0];
    float z0 = Tin[s0];
    float P0 = 0.0f;
    const float dt = 1.0f / (float)NSTEPS;
    const float2v one = {1.0f, 1.0f};
    const floatx16 zero16 = (floatx16)0.0f;

    for (int step = 0; step < NSTEPS; ++step) {
        float kz0 = 0.0f, accz0 = 0.0f;
#pragma unroll 1
        for (int s4 = 0; s4 < 4; ++s4) {
            const float a = (s4 == 0) ? 0.0f : ((s4 == 3) ? dt : 0.5f * dt);
            const float w = ((s4 == 0) | (s4 == 3)) ? (dt * (1.0f / 6.0f))
                                                    : (dt * (1.0f / 3.0f));
            const float zi0 = fmaf(a, kz0, z0);

            // ---- B-frag prep: h1 (bf16 cvt_pk) and s*d1 (bf16 trunc) ----
            unsigned bh[2][4], bd[2][4];
#pragma unroll
            for (int t = 0; t < 2; ++t)
#pragma unroll
                for (int p = 0; p < 4; ++p) {
                    const float2v xs = vfma(float2v{zi0, zi0}, w1zv[t][p], c1v[t][p]);
                    const float2v h  = tanh_pk(xs);
                    bh[t][p] = cvtpk_bf16(h.x, h.y);
                    const float2v hh = h * h;
                    bd[t][p] = pack2bf_trunc(vfma(hh, -w1zv[t][p], w1zv[t][p]));
                }
            const short8 Bh0 = __builtin_bit_cast(short8, U128{bh[0][0], bh[0][1], bh[0][2], bh[0][3]});
            const short8 Bh1 = __builtin_bit_cast(short8, U128{bh[1][0], bh[1][1], bh[1][2], bh[1][3]});
            const short8 Bd0 = __builtin_bit_cast(short8, U128{bd[0][0], bd[0][1], bd[0][2], bd[0][3]});
            const short8 Bd1 = __builtin_bit_cast(short8, U128{bd[1][0], bd[1][1], bd[1][2], bd[1][3]});

            // ---- transposed layer-2: D[u][sample] = (s*W2) @ h1^T ----
            floatx16 Dh = __builtin_amdgcn_mfma_f32_32x32x16_bf16(Wlo[0], Bh0, cinit, 0, 0, 0);
            Dh = __builtin_amdgcn_mfma_f32_32x32x16_bf16(Whi[0], Bh0, Dh, 0, 0, 0);
            Dh = __builtin_amdgcn_mfma_f32_32x32x16_bf16(Wlo[1], Bh1, Dh, 0, 0, 0);
            Dh = __builtin_amdgcn_mfma_f32_32x32x16_bf16(Whi[1], Bh1, Dh, 0, 0, 0);
            floatx16 Dd = __builtin_amdgcn_mfma_f32_32x32x16_bf16(Whi[0], Bd0, zero16, 0, 0, 0);
            Dd = __builtin_amdgcn_mfma_f32_32x32x16_bf16(Whi[1], Bd1, Dd, 0, 0, 0);

            // ---- lane-local W3 contraction over the 16 local D rows ----
            float2v az = {0.0f, 0.0f}, dv = {0.0f, 0.0f};
#pragma unroll
            for (int g = 0; g < 8; ++g) {
                const float2v h2 = tanh_pk(float2v{Dh[2 * g], Dh[2 * g + 1]});
                az = vfma(h2, w3p[g], az);
                const float2v ua = vfma(h2, -h2, one);
                const float2v tt = float2v{Dd[2 * g], Dd[2 * g + 1]} * w3p[g];
                dv = vfma(tt, ua, dv);
            }

            // full row-sum: self + lane^32 partner (VALU exchange)
            kz0 = xsum32(az.x + az.y) + b3v;
            accz0 = fmaf(w, kz0, accz0);
            P0 = fmaf(w, dv.x + dv.y, P0);   // partner exchange deferred
        }
        z0 += accz0;
    }

    // ---- epilogue: one partner exchange for dlog; s^-2 once ----
    const float d0 = xsum32(P0) * is2;

    if (hi == 0 && sgu < B) {                // partner lane holds identical copy
        out[sgu] = z0;
        out[(size_t)B + sgu] = d0;
    }
}

extern "C" void kernel_launch(void* const* d_in, const int* in_sizes, int n_in,
                              void* d_out, int out_size, void* d_ws, size_t ws_size,
                              hipStream_t stream) {
    const float* T    = (const float*)d_in[0];
    const float* cond = (const float*)d_in[1];
    const float* W1   = (const float*)d_in[2];
    const float* b1   = (const float*)d_in[3];
    const float* W2   = (const float*)d_in[4];
    const float* b2   = (const float*)d_in[5];
    const float* W3   = (const float*)d_in[6];
    const float* b3   = (const float*)d_in[7];
    float* out = (float*)d_out;

    const int B = in_sizes[0];
    const int grid = (B + 127) / 128;
    cnf_mfma<<<grid, 256, 0, stream>>>(T, cond, W1, b1, W2, b2, W3, b3, out, B);
}

// Round 12
// 745.802 us; speedup vs baseline: 4.5780x; 4.5780x over previous
//
#include <hip/hip_runtime.h>

// ConditionalCNF via MFMA (round 17): r15 base (verified 784us steady,
// absmax 0.07092285) + explicit packed-FP32 VALU ops.
// r16 post-mortem: forcing VGPR<=64 spilled the ~78-reg persistent set
// (FETCH 11.6GB, HBM 48%, 3414us) -- occupancy axis CLOSED; reverted.
// This round: the 112 element-wise float2v insts per s4 (prep xs/hh/d-nfma,
// h2-loop az/ua/tt/dv) are emitted as 2x scalar v_fma/v_mul by the compiler
// (busy-model fits only close with scalarized counts).  gfx90a+ has
// full-rate packed FP32 (v_pk_fma_f32 / v_pk_mul_f32, even-aligned VGPR
// pairs, IEEE-identical per element).  Inline asm emits them directly;
// neg_lo/neg_hi:[1,0,0] gives the -a*b+c forms.  -224 cyc/s4 (~10% busy),
// zero numerics change (same IEEE ops in same order -> absmax bit-identical).
//
// Layouts (HW-verified per guide m74/m101):
//   A-frag 32x32x16:  A[m=lane&31][k=(lane>>5)*8+j]
//   B-frag 32x32x16:  B[k=(lane>>5)*8+j][n=lane&31]
//   C/D:              col=lane&31, row=(reg&3)+8*(reg>>2)+4*(lane>>5)

typedef __attribute__((ext_vector_type(8))) short short8;
typedef __attribute__((ext_vector_type(2))) float float2v;
typedef __attribute__((ext_vector_type(16))) float floatx16;

constexpr int NSTEPS = 20;
constexpr float SCL = 2.8853900817779268f;   // 2*log2(e)

struct U128 { unsigned a, b, c, d; };

__device__ __forceinline__ float fexp2(float x) {
#if __has_builtin(__builtin_amdgcn_exp2f)
    return __builtin_amdgcn_exp2f(x);
#else
    return exp2f(x);
#endif
}

// ---- packed f32 VALU (gfx90a+; single-issue, both elements, IEEE) ----
__device__ __forceinline__ float2v pk_fma(float2v a, float2v b, float2v c) {
    float2v d;
    asm("v_pk_fma_f32 %0, %1, %2, %3" : "=v"(d) : "v"(a), "v"(b), "v"(c));
    return d;
}
// d = -a*b + c (per element) via neg modifiers on src0
__device__ __forceinline__ float2v pk_nfma(float2v a, float2v b, float2v c) {
    float2v d;
    asm("v_pk_fma_f32 %0, %1, %2, %3 neg_lo:[1,0,0] neg_hi:[1,0,0]"
        : "=v"(d) : "v"(a), "v"(b), "v"(c));
    return d;
}
__device__ __forceinline__ float2v pk_mul(float2v a, float2v b) {
    float2v d;
    asm("v_pk_mul_f32 %0, %1, %2" : "=v"(d) : "v"(a), "v"(b));
    return d;
}

// packed tanh, pre-scaled inputs xs = 2*log2(e)*x.  tanh = 1 - 2/(exp2+1),
// ONE rcp per pair via reciprocal sharing; all constants inline.  (Internals
// stay scalar: exp/rcp are scalar-only, and the cross-element dx*dy trick
// doesn't pack.)
__device__ __forceinline__ float2v tanh_pk(float2v xs) {
    const float ex = fexp2(xs.x);
    const float ey = fexp2(xs.y);
    const float dx = ex + 1.0f;
    const float dy = ey + 1.0f;
    const float rr = __builtin_amdgcn_rcpf(dx * dy);
    const float q  = rr * -2.0f;
    return float2v{fmaf(q, dy, 1.0f), fmaf(q, dx, 1.0f)};
}

__device__ __forceinline__ unsigned cvtpk_bf16(float a, float b) {
    unsigned r;
    asm("v_cvt_pk_bf16_f32 %0, %1, %2" : "=v"(r) : "v"(a), "v"(b));
    return r;
}

__device__ __forceinline__ unsigned pack2bf(float a, float b) {
    unsigned ua = __builtin_bit_cast(unsigned, a) + 0x8000u;
    unsigned ub = __builtin_bit_cast(unsigned, b) + 0x8000u;
    return __builtin_amdgcn_perm(ub, ua, 0x07060302u);
}
__device__ __forceinline__ unsigned pack2bf_trunc(float2v v) {
    return __builtin_amdgcn_perm(__builtin_bit_cast(unsigned, v.y),
                                 __builtin_bit_cast(unsigned, v.x), 0x07060302u);
}
__device__ __forceinline__ float bf2f(unsigned bf) {
    return __builtin_bit_cast(float, bf << 16);
}

// x + x[lane^32] on the VALU pipe (verified r15, absmax bit-identical).
// Two distinct "+v" operands cannot alias; after v_permlane32_swap_b32 a,b
// (a_hi <-> b_lo), a+b is the symmetric pair-sum for every lane.
__device__ __forceinline__ float xsum32(float x) {
    float a = x, b = x;
    asm("v_permlane32_swap_b32 %0, %1" : "+v"(a), "+v"(b));
    return a + b;
}

__global__ __launch_bounds__(256, 3) void cnf_mfma(
    const float* __restrict__ Tin, const float* __restrict__ cond,
    const float* __restrict__ W1, const float* __restrict__ b1,
    const float* __restrict__ W2, const float* __restrict__ b2,
    const float* __restrict__ W3, const float* __restrict__ b3,
    float* __restrict__ out, int B)
{
    const int tid   = threadIdx.x;
    const int lane  = tid & 63;
    const int wbase = blockIdx.x * 256 + (tid >> 6) * 64;

    const int c  = lane & 31;          // D col = sample col; W2 row (A m)
    const int hi = lane >> 5;          // k-group for frags; D row-half

    const float is2 = 1.0f / (SCL * SCL);

    // ---- W2 A-frags: A[m=c][k = 16t + hi*8 + j], hi/lo bf16 split ----
    short8 Whi[2], Wlo[2];
#pragma unroll
    for (int t = 0; t < 2; ++t) {
        const float* w2r = W2 + c * 32 + 16 * t + hi * 8;
        unsigned hu[4], lu[4];
#pragma unroll
        for (int p = 0; p < 4; ++p) {
            const float w0 = SCL * w2r[2 * p], w1v = SCL * w2r[2 * p + 1];
            const unsigned h0 = (__builtin_bit_cast(unsigned, w0) + 0x8000u) >> 16;
            const unsigned h1 = (__builtin_bit_cast(unsigned, w1v) + 0x8000u) >> 16;
            hu[p] = h0 | (h1 << 16);
            lu[p] = pack2bf(w0 - bf2f(h0), w1v - bf2f(h1));
        }
        Whi[t] = __builtin_bit_cast(short8, U128{hu[0], hu[1], hu[2], hu[3]});
        Wlo[t] = __builtin_bit_cast(short8, U128{lu[0], lu[1], lu[2], lu[3]});
    }

    // ---- per-lane D-row constants: u(reg) = (reg&3) + 8*(reg>>2) + 4*hi ----
    floatx16 cinit;
    float2v w3p[8];
#pragma unroll
    for (int g = 0; g < 8; ++g) {
        const int u0 = ((2 * g) & 3) + 8 * (g >> 1) + 4 * hi;
        cinit[2 * g]     = SCL * b2[u0];
        cinit[2 * g + 1] = SCL * b2[u0 + 1];
        w3p[g] = float2v{W3[u0], W3[u0 + 1]};
    }

    // ---- layer-1 constants: k(t,j) = 16t + hi*8 + j ----
    float2v w1zv[2][4];
#pragma unroll
    for (int t = 0; t < 2; ++t)
#pragma unroll
        for (int p = 0; p < 4; ++p) {
            const int k = 16 * t + hi * 8 + 2 * p;
            w1zv[t][p] = float2v{SCL * W1[k * 9], SCL * W1[(k + 1) * 9]};
        }

    int s0 = wbase + c;      if (s0 > B - 1) s0 = B - 1;
    int s1 = wbase + 32 + c; if (s1 > B - 1) s1 = B - 1;

    float cd0[8], cd1[8];
    {
        const float4* c4 = reinterpret_cast<const float4*>(cond + (size_t)s0 * 8);
        const float4 ca = c4[0], cb = c4[1];
        cd0[0]=ca.x; cd0[1]=ca.y; cd0[2]=ca.z; cd0[3]=ca.w;
        cd0[4]=cb.x; cd0[5]=cb.y; cd0[6]=cb.z; cd0[7]=cb.w;
    }
    {
        const float4* c4 = reinterpret_cast<const float4*>(cond + (size_t)s1 * 8);
        const float4 ca = c4[0], cb = c4[1];
        cd1[0]=ca.x; cd1[1]=ca.y; cd1[2]=ca.z; cd1[3]=ca.w;
        cd1[4]=cb.x; cd1[5]=cb.y; cd1[6]=cb.z; cd1[7]=cb.w;
    }

    // c1[hf][t][p]: s*(b1 + cond.W1row) for k = 16t + hi*8 + {2p,2p+1}
    float2v c1v[2][2][4];
#pragma unroll
    for (int t = 0; t < 2; ++t) {
        float c1a[8], c1b[8];
#pragma unroll
        for (int j = 0; j < 8; ++j) {
            const int k = 16 * t + hi * 8 + j;
            const float* wr = W1 + k * 9 + 1;
            float a0 = b1[k], a1 = a0;
#pragma unroll
            for (int jj = 0; jj < 8; ++jj) {
                a0 = fmaf(cd0[jj], wr[jj], a0);
                a1 = fmaf(cd1[jj], wr[jj], a1);
            }
            c1a[j] = SCL * a0;
            c1b[j] = SCL * a1;
        }
#pragma unroll
        for (int p = 0; p < 4; ++p) {
            c1v[0][t][p] = float2v{c1a[2 * p], c1a[2 * p + 1]};
            c1v[1][t][p] = float2v{c1b[2 * p], c1b[2 * p + 1]};
        }
    }

    const float b3v = b3[0];
    float z0 = Tin[s0], z1 = Tin[s1];
    float P0 = 0.0f, P1 = 0.0f;
    const float dt = 1.0f / (float)NSTEPS;
    const float2v one = {1.0f, 1.0f};
    const floatx16 zero16 = (floatx16)0.0f;

    // per-half evaluation: zi -> (az partial, dv partial) over this lane's rows
    auto half_eval = [&](float zi, const float2v (&c1h)[2][4],
                         float& azs, float& dvs) {
        const float2v zz = {zi, zi};
        unsigned bh[2][4], bd[2][4];
#pragma unroll
        for (int t = 0; t < 2; ++t)
#pragma unroll
            for (int p = 0; p < 4; ++p) {
                const float2v xs = pk_fma(zz, w1zv[t][p], c1h[t][p]);
                const float2v h  = tanh_pk(xs);
                bh[t][p] = cvtpk_bf16(h.x, h.y);
                const float2v hh = pk_mul(h, h);
                bd[t][p] = pack2bf_trunc(pk_nfma(hh, w1zv[t][p], w1zv[t][p]));
            }
        const short8 Bh0 = __builtin_bit_cast(short8, U128{bh[0][0], bh[0][1], bh[0][2], bh[0][3]});
        const short8 Bh1 = __builtin_bit_cast(short8, U128{bh[1][0], bh[1][1], bh[1][2], bh[1][3]});
        const short8 Bd0 = __builtin_bit_cast(short8, U128{bd[0][0], bd[0][1], bd[0][2], bd[0][3]});
        const short8 Bd1 = __builtin_bit_cast(short8, U128{bd[1][0], bd[1][1], bd[1][2], bd[1][3]});

        floatx16 Dh = __builtin_amdgcn_mfma_f32_32x32x16_bf16(Wlo[0], Bh0, cinit, 0, 0, 0);
        Dh = __builtin_amdgcn_mfma_f32_32x32x16_bf16(Whi[0], Bh0, Dh, 0, 0, 0);
        Dh = __builtin_amdgcn_mfma_f32_32x32x16_bf16(Wlo[1], Bh1, Dh, 0, 0, 0);
        Dh = __builtin_amdgcn_mfma_f32_32x32x16_bf16(Whi[1], Bh1, Dh, 0, 0, 0);
        floatx16 Dd = __builtin_amdgcn_mfma_f32_32x32x16_bf16(Whi[0], Bd0, zero16, 0, 0, 0);
        Dd = __builtin_amdgcn_mfma_f32_32x32x16_bf16(Whi[1], Bd1, Dd, 0, 0, 0);

        float2v az = {0.0f, 0.0f}, dv = {0.0f, 0.0f};
#pragma unroll
        for (int g = 0; g < 8; ++g) {
            const float2v h2 = tanh_pk(float2v{Dh[2 * g], Dh[2 * g + 1]});
            az = pk_fma(h2, w3p[g], az);
            const float2v ua = pk_nfma(h2, h2, one);
            const float2v tt = pk_mul(float2v{Dd[2 * g], Dd[2 * g + 1]}, w3p[g]);
            dv = pk_fma(tt, ua, dv);
        }
        azs = az.x + az.y;
        dvs = dv.x + dv.y;
    };

    for (int step = 0; step < NSTEPS; ++step) {
        float kz0 = 0.0f, kz1 = 0.0f, accz0 = 0.0f, accz1 = 0.0f;
#pragma unroll 1
        for (int s4 = 0; s4 < 4; ++s4) {
            const float a = (s4 == 0) ? 0.0f : ((s4 == 3) ? dt : 0.5f * dt);
            const float w = ((s4 == 0) | (s4 == 3)) ? (dt * (1.0f / 6.0f))
                                                    : (dt * (1.0f / 3.0f));
            const float zi0 = fmaf(a, kz0, z0);
            const float zi1 = fmaf(a, kz1, z1);

            float az0, dv0, az1, dv1;
            half_eval(zi0, c1v[0], az0, dv0);
            half_eval(zi1, c1v[1], az1, dv1);

            // full row-sum: self + lane^32 partner, VALU-pipe exchange
            kz0 = xsum32(az0) + b3v;
            kz1 = xsum32(az1) + b3v;
            accz0 = fmaf(w, kz0, accz0);
            accz1 = fmaf(w, kz1, accz1);
            P0 = fmaf(w, dv0, P0);     // partner exchange deferred to epilogue
            P1 = fmaf(w, dv1, P1);
        }
        z0 += accz0;
        z1 += accz1;
    }

    // ---- epilogue: one partner exchange per half for dlog; s^-2 once ----
    const float d0 = xsum32(P0) * is2;
    const float d1 = xsum32(P1) * is2;

    const int sg = wbase + lane;       // lane<32 -> half0 col=lane; else half1
    if (sg < B) {
        out[sg] = hi ? z1 : z0;
        out[(size_t)B + sg] = hi ? d1 : d0;
    }
}

extern "C" void kernel_launch(void* const* d_in, const int* in_sizes, int n_in,
                              void* d_out, int out_size, void* d_ws, size_t ws_size,
                              hipStream_t stream) {
    const float* T    = (const float*)d_in[0];
    const float* cond = (const float*)d_in[1];
    const float* W1   = (const float*)d_in[2];
    const float* b1   = (const float*)d_in[3];
    const float* W2   = (const float*)d_in[4];
    const float* b2   = (const float*)d_in[5];
    const float* W3   = (const float*)d_in[6];
    const float* b3   = (const float*)d_in[7];
    float* out = (float*)d_out;

    const int B = in_sizes[0];
    const int grid = (B + 255) / 256;
    cnf_mfma<<<grid, 256, 0, stream>>>(T, cond, W1, b1, W2, b2, W3, b3, out, B);
}

// Round 13
// 726.901 us; speedup vs baseline: 4.6971x; 1.0260x over previous
//
#include <hip/hip_runtime.h>

// ConditionalCNF via MFMA (round 18 = verified round 15, FINAL REVERT).
// r17 post-mortem: v_pk_fma_f32 is throughput-equivalent to 2x scalar fma on
// CDNA4 (equal busy product, +idle from asm pinning) -- packed-f32 axis
// closed.  All axes now experimentally closed:
//   TRANS: 2-exp/tanh algorithmic floor (poly/rcp rewrites wash, r8/r9/r11)
//   main:  FLOP-throughput-bound (r17), ~static floor
//   occupancy: live-set floor ~76 VGPR; <=64 spills (r16, 11.6GB scratch)
//   latency: cross-lane exchange already hidden (r15 null)
//   issue port: VALUBusy 78.7 + MfmaUtil 15.1 ~= 94% saturated
// This kernel: 32x32x16 transposed layer-2, register-resident z (no
// broadcast), permlane32 pair-sum (alias-proof inline asm), deferred dlog
// reduction, Whi-only d-path, shared-rcp tanh.  729.9us, absmax 0.07092285.
//
// Layouts (HW-verified per guide m74/m101):
//   A-frag 32x32x16:  A[m=lane&31][k=(lane>>5)*8+j]
//   B-frag 32x32x16:  B[k=(lane>>5)*8+j][n=lane&31]
//   C/D:              col=lane&31, row=(reg&3)+8*(reg>>2)+4*(lane>>5)

typedef __attribute__((ext_vector_type(8))) short short8;
typedef __attribute__((ext_vector_type(2))) float float2v;
typedef __attribute__((ext_vector_type(16))) float floatx16;

constexpr int NSTEPS = 20;
constexpr float SCL = 2.8853900817779268f;   // 2*log2(e)

struct U128 { unsigned a, b, c, d; };

__device__ __forceinline__ float fexp2(float x) {
#if __has_builtin(__builtin_amdgcn_exp2f)
    return __builtin_amdgcn_exp2f(x);
#else
    return exp2f(x);
#endif
}

__device__ __forceinline__ float2v vfma(float2v a, float2v b, float2v c) {
#if __has_builtin(__builtin_elementwise_fma)
    return __builtin_elementwise_fma(a, b, c);
#else
    float2v d; d.x = fmaf(a.x, b.x, c.x); d.y = fmaf(a.y, b.y, c.y); return d;
#endif
}

// packed tanh, pre-scaled inputs xs = 2*log2(e)*x.  tanh = 1 - 2/(exp2+1),
// ONE rcp per pair via reciprocal sharing; all constants inline.
__device__ __forceinline__ float2v tanh_pk(float2v xs) {
    const float ex = fexp2(xs.x);
    const float ey = fexp2(xs.y);
    const float dx = ex + 1.0f;
    const float dy = ey + 1.0f;
    const float rr = __builtin_amdgcn_rcpf(dx * dy);
    const float q  = rr * -2.0f;
    return float2v{fmaf(q, dy, 1.0f), fmaf(q, dx, 1.0f)};
}

__device__ __forceinline__ unsigned cvtpk_bf16(float a, float b) {
    unsigned r;
    asm("v_cvt_pk_bf16_f32 %0, %1, %2" : "=v"(r) : "v"(a), "v"(b));
    return r;
}

__device__ __forceinline__ unsigned pack2bf(float a, float b) {
    unsigned ua = __builtin_bit_cast(unsigned, a) + 0x8000u;
    unsigned ub = __builtin_bit_cast(unsigned, b) + 0x8000u;
    return __builtin_amdgcn_perm(ub, ua, 0x07060302u);
}
__device__ __forceinline__ unsigned pack2bf_trunc(float2v v) {
    return __builtin_amdgcn_perm(__builtin_bit_cast(unsigned, v.y),
                                 __builtin_bit_cast(unsigned, v.x), 0x07060302u);
}
__device__ __forceinline__ float bf2f(unsigned bf) {
    return __builtin_bit_cast(float, bf << 16);
}

// x + x[lane^32] on the VALU pipe (verified r15, absmax bit-identical).
// Two distinct "+v" operands cannot alias; after v_permlane32_swap_b32 a,b
// (a_hi <-> b_lo), a+b is the symmetric pair-sum for every lane.
__device__ __forceinline__ float xsum32(float x) {
    float a = x, b = x;
    asm("v_permlane32_swap_b32 %0, %1" : "+v"(a), "+v"(b));
    return a + b;
}

__global__ __launch_bounds__(256, 3) void cnf_mfma(
    const float* __restrict__ Tin, const float* __restrict__ cond,
    const float* __restrict__ W1, const float* __restrict__ b1,
    const float* __restrict__ W2, const float* __restrict__ b2,
    const float* __restrict__ W3, const float* __restrict__ b3,
    float* __restrict__ out, int B)
{
    const int tid   = threadIdx.x;
    const int lane  = tid & 63;
    const int wbase = blockIdx.x * 256 + (tid >> 6) * 64;

    const int c  = lane & 31;          // D col = sample col; W2 row (A m)
    const int hi = lane >> 5;          // k-group for frags; D row-half

    const float is2 = 1.0f / (SCL * SCL);

    // ---- W2 A-frags: A[m=c][k = 16t + hi*8 + j], hi/lo bf16 split ----
    short8 Whi[2], Wlo[2];
#pragma unroll
    for (int t = 0; t < 2; ++t) {
        const float* w2r = W2 + c * 32 + 16 * t + hi * 8;
        unsigned hu[4], lu[4];
#pragma unroll
        for (int p = 0; p < 4; ++p) {
            const float w0 = SCL * w2r[2 * p], w1v = SCL * w2r[2 * p + 1];
            const unsigned h0 = (__builtin_bit_cast(unsigned, w0) + 0x8000u) >> 16;
            const unsigned h1 = (__builtin_bit_cast(unsigned, w1v) + 0x8000u) >> 16;
            hu[p] = h0 | (h1 << 16);
            lu[p] = pack2bf(w0 - bf2f(h0), w1v - bf2f(h1));
        }
        Whi[t] = __builtin_bit_cast(short8, U128{hu[0], hu[1], hu[2], hu[3]});
        Wlo[t] = __builtin_bit_cast(short8, U128{lu[0], lu[1], lu[2], lu[3]});
    }

    // ---- per-lane D-row constants: u(reg) = (reg&3) + 8*(reg>>2) + 4*hi ----
    floatx16 cinit;
    float2v w3p[8];
#pragma unroll
    for (int g = 0; g < 8; ++g) {
        const int u0 = ((2 * g) & 3) + 8 * (g >> 1) + 4 * hi;
        cinit[2 * g]     = SCL * b2[u0];
        cinit[2 * g + 1] = SCL * b2[u0 + 1];
        w3p[g] = float2v{W3[u0], W3[u0 + 1]};
    }

    // ---- layer-1 constants: k(t,j) = 16t + hi*8 + j ----
    float2v w1zv[2][4];
#pragma unroll
    for (int t = 0; t < 2; ++t)
#pragma unroll
        for (int p = 0; p < 4; ++p) {
            const int k = 16 * t + hi * 8 + 2 * p;
            w1zv[t][p] = float2v{SCL * W1[k * 9], SCL * W1[(k + 1) * 9]};
        }

    int s0 = wbase + c;      if (s0 > B - 1) s0 = B - 1;
    int s1 = wbase + 32 + c; if (s1 > B - 1) s1 = B - 1;

    float cd0[8], cd1[8];
    {
        const float4* c4 = reinterpret_cast<const float4*>(cond + (size_t)s0 * 8);
        const float4 ca = c4[0], cb = c4[1];
        cd0[0]=ca.x; cd0[1]=ca.y; cd0[2]=ca.z; cd0[3]=ca.w;
        cd0[4]=cb.x; cd0[5]=cb.y; cd0[6]=cb.z; cd0[7]=cb.w;
    }
    {
        const float4* c4 = reinterpret_cast<const float4*>(cond + (size_t)s1 * 8);
        const float4 ca = c4[0], cb = c4[1];
        cd1[0]=ca.x; cd1[1]=ca.y; cd1[2]=ca.z; cd1[3]=ca.w;
        cd1[4]=cb.x; cd1[5]=cb.y; cd1[6]=cb.z; cd1[7]=cb.w;
    }

    // c1[hf][t][p]: s*(b1 + cond.W1row) for k = 16t + hi*8 + {2p,2p+1}
    float2v c1v[2][2][4];
#pragma unroll
    for (int t = 0; t < 2; ++t) {
        float c1a[8], c1b[8];
#pragma unroll
        for (int j = 0; j < 8; ++j) {
            const int k = 16 * t + hi * 8 + j;
            const float* wr = W1 + k * 9 + 1;
            float a0 = b1[k], a1 = a0;
#pragma unroll
            for (int jj = 0; jj < 8; ++jj) {
                a0 = fmaf(cd0[jj], wr[jj], a0);
                a1 = fmaf(cd1[jj], wr[jj], a1);
            }
            c1a[j] = SCL * a0;
            c1b[j] = SCL * a1;
        }
#pragma unroll
        for (int p = 0; p < 4; ++p) {
            c1v[0][t][p] = float2v{c1a[2 * p], c1a[2 * p + 1]};
            c1v[1][t][p] = float2v{c1b[2 * p], c1b[2 * p + 1]};
        }
    }

    const float b3v = b3[0];
    float z0 = Tin[s0], z1 = Tin[s1];
    float P0 = 0.0f, P1 = 0.0f;
    const float dt = 1.0f / (float)NSTEPS;
    const float2v one = {1.0f, 1.0f};
    const floatx16 zero16 = (floatx16)0.0f;

    // per-half evaluation: zi -> (az partial, dv partial) over this lane's rows
    auto half_eval = [&](float zi, const float2v (&c1h)[2][4],
                         float& azs, float& dvs) {
        unsigned bh[2][4], bd[2][4];
#pragma unroll
        for (int t = 0; t < 2; ++t)
#pragma unroll
            for (int p = 0; p < 4; ++p) {
                const float2v xs = vfma(float2v{zi, zi}, w1zv[t][p], c1h[t][p]);
                const float2v h  = tanh_pk(xs);
                bh[t][p] = cvtpk_bf16(h.x, h.y);
                const float2v hh = h * h;
                bd[t][p] = pack2bf_trunc(vfma(hh, -w1zv[t][p], w1zv[t][p]));
            }
        const short8 Bh0 = __builtin_bit_cast(short8, U128{bh[0][0], bh[0][1], bh[0][2], bh[0][3]});
        const short8 Bh1 = __builtin_bit_cast(short8, U128{bh[1][0], bh[1][1], bh[1][2], bh[1][3]});
        const short8 Bd0 = __builtin_bit_cast(short8, U128{bd[0][0], bd[0][1], bd[0][2], bd[0][3]});
        const short8 Bd1 = __builtin_bit_cast(short8, U128{bd[1][0], bd[1][1], bd[1][2], bd[1][3]});

        floatx16 Dh = __builtin_amdgcn_mfma_f32_32x32x16_bf16(Wlo[0], Bh0, cinit, 0, 0, 0);
        Dh = __builtin_amdgcn_mfma_f32_32x32x16_bf16(Whi[0], Bh0, Dh, 0, 0, 0);
        Dh = __builtin_amdgcn_mfma_f32_32x32x16_bf16(Wlo[1], Bh1, Dh, 0, 0, 0);
        Dh = __builtin_amdgcn_mfma_f32_32x32x16_bf16(Whi[1], Bh1, Dh, 0, 0, 0);
        floatx16 Dd = __builtin_amdgcn_mfma_f32_32x32x16_bf16(Whi[0], Bd0, zero16, 0, 0, 0);
        Dd = __builtin_amdgcn_mfma_f32_32x32x16_bf16(Whi[1], Bd1, Dd, 0, 0, 0);

        float2v az = {0.0f, 0.0f}, dv = {0.0f, 0.0f};
#pragma unroll
        for (int g = 0; g < 8; ++g) {
            const float2v h2 = tanh_pk(float2v{Dh[2 * g], Dh[2 * g + 1]});
            az = vfma(h2, w3p[g], az);
            const float2v ua = vfma(h2, -h2, one);
            const float2v tt = float2v{Dd[2 * g], Dd[2 * g + 1]} * w3p[g];
            dv = vfma(tt, ua, dv);
        }
        azs = az.x + az.y;
        dvs = dv.x + dv.y;
    };

    for (int step = 0; step < NSTEPS; ++step) {
        float kz0 = 0.0f, kz1 = 0.0f, accz0 = 0.0f, accz1 = 0.0f;
#pragma unroll 1
        for (int s4 = 0; s4 < 4; ++s4) {
            const float a = (s4 == 0) ? 0.0f : ((s4 == 3) ? dt : 0.5f * dt);
            const float w = ((s4 == 0) | (s4 == 3)) ? (dt * (1.0f / 6.0f))
                                                    : (dt * (1.0f / 3.0f));
            const float zi0 = fmaf(a, kz0, z0);
            const float zi1 = fmaf(a, kz1, z1);

            float az0, dv0, az1, dv1;
            half_eval(zi0, c1v[0], az0, dv0);
            half_eval(zi1, c1v[1], az1, dv1);

            // full row-sum: self + lane^32 partner, VALU-pipe exchange
            kz0 = xsum32(az0) + b3v;
            kz1 = xsum32(az1) + b3v;
            accz0 = fmaf(w, kz0, accz0);
            accz1 = fmaf(w, kz1, accz1);
            P0 = fmaf(w, dv0, P0);     // partner exchange deferred to epilogue
            P1 = fmaf(w, dv1, P1);
        }
        z0 += accz0;
        z1 += accz1;
    }

    // ---- epilogue: one partner exchange per half for dlog; s^-2 once ----
    const float d0 = xsum32(P0) * is2;
    const float d1 = xsum32(P1) * is2;

    const int sg = wbase + lane;       // lane<32 -> half0 col=lane; else half1
    if (sg < B) {
        out[sg] = hi ? z1 : z0;
        out[(size_t)B + sg] = hi ? d1 : d0;
    }
}

extern "C" void kernel_launch(void* const* d_in, const int* in_sizes, int n_in,
                              void* d_out, int out_size, void* d_ws, size_t ws_size,
                              hipStream_t stream) {
    const float* T    = (const float*)d_in[0];
    const float* cond = (const float*)d_in[1];
    const float* W1   = (const float*)d_in[2];
    const float* b1   = (const float*)d_in[3];
    const float* W2   = (const float*)d_in[4];
    const float* b2   = (const float*)d_in[5];
    const float* W3   = (const float*)d_in[6];
    const float* b3   = (const float*)d_in[7];
    float* out = (float*)d_out;

    const int B = in_sizes[0];
    const int grid = (B + 255) / 256;
    cnf_mfma<<<grid, 256, 0, stream>>>(T, cond, W1, b1, W2, b2, W3, b3, out, B);
}